// Round 7
// baseline (216.658 us; speedup 1.0000x reference)
//
#include <hip/hip_runtime.h>
#include <math.h>

// Problem constants (fixed by the reference)
#define T_    1024      // B*S tokens
#define H_    512       // hidden
#define I_    1024      // intermediate
#define E_    64        // routed experts
#define K_    4         // top-k
#define NPAIR (T_*K_)   // 4096 routed (token,slot) pairs
#define NENT  (NPAIR + T_)  // + shared-expert entries at [NPAIR + t]

#define BM 128          // rows per work block
#define BN 64           // output cols per block
#define BKS 32          // k-step (elements) -> small tiles, dbuf fits 3 blk/CU
#define MAXWORK 160
#define NT1 (H_/BKS)    // 16
#define NT2 (I_/BKS)    // 32

typedef float  f32x4  __attribute__((ext_vector_type(4)));
typedef short  bf16x8 __attribute__((ext_vector_type(8)));

// single per-step sync: loads issued this step (next tile) must land; they
// had the whole compute phase to fly. lgkmcnt guards ds_read completion.
#define STEP_SYNC() asm volatile("s_waitcnt vmcnt(0) lgkmcnt(0)\n\ts_barrier" ::: "memory")

__device__ __forceinline__ ushort f2bf(float f) {
    uint u = __float_as_uint(f);
    u += 0x7fffu + ((u >> 16) & 1u);   // round-to-nearest-even
    return (ushort)(u >> 16);
}
// packed f32->bf16 (RNE, same result as f2bf) - 1 VALU op per 2 elements
__device__ __forceinline__ bf16x8 cvt8pk(f32x4 a, f32x4 b) {
    union { uint u[4]; bf16x8 v; } r;
    asm("v_cvt_pk_bf16_f32 %0, %1, %2" : "=v"(r.u[0]) : "v"(a[0]), "v"(a[1]));
    asm("v_cvt_pk_bf16_f32 %0, %1, %2" : "=v"(r.u[1]) : "v"(a[2]), "v"(a[3]));
    asm("v_cvt_pk_bf16_f32 %0, %1, %2" : "=v"(r.u[2]) : "v"(b[0]), "v"(b[1]));
    asm("v_cvt_pk_bf16_f32 %0, %1, %2" : "=v"(r.u[3]) : "v"(b[2]), "v"(b[3]));
    return r.v;
}

// async global->LDS, 16B per lane; LDS dest = wave-uniform base + lane*16
__device__ __forceinline__ void gload16(const void* g, void* lds) {
    __builtin_amdgcn_global_load_lds(
        (const __attribute__((address_space(1))) unsigned int*)g,
        (__attribute__((address_space(3))) unsigned int*)lds, 16, 0, 0);
}

// ---------------------------------------------------------------------------
// x -> bf16 pre-pass (2 MB, ~2 us)
// ---------------------------------------------------------------------------
__global__ __launch_bounds__(256) void x_cvt(const float* __restrict__ x,
                                             ushort* __restrict__ xb)
{
    const int i = blockIdx.x*256 + threadIdx.x;     // T_*H_/4 float4s
    float4 v = reinterpret_cast<const float4*>(x)[i];
    reinterpret_cast<ushort4*>(xb)[i] =
        make_ushort4(f2bf(v.x), f2bf(v.y), f2bf(v.z), f2bf(v.w));
}

// ---------------------------------------------------------------------------
// Router: one 64-thread block per token.
// ---------------------------------------------------------------------------
__global__ __launch_bounds__(64) void moe_router(
    const float* __restrict__ x, const float* __restrict__ rw,
    const float* __restrict__ rb, const float* __restrict__ eb,
    int* __restrict__ idx_out, float* __restrict__ gate_out)
{
    const int t = blockIdx.x;
    const int lane = threadIdx.x;  // 0..63
    __shared__ float xs[H_];
    __shared__ float lg[E_];
    __shared__ float bs[E_];
    for (int i = lane; i < H_; i += 64) xs[i] = x[(size_t)t*H_ + i];
    bs[lane] = eb[lane];
    __syncthreads();
    float acc = 0.f;
    const float* wrow = rw + (size_t)lane*H_;
    for (int k = 0; k < H_; k += 4) {
        float4 w4 = *reinterpret_cast<const float4*>(wrow + k);
        acc = fmaf(xs[k+0], w4.x, acc);
        acc = fmaf(xs[k+1], w4.y, acc);
        acc = fmaf(xs[k+2], w4.z, acc);
        acc = fmaf(xs[k+3], w4.w, acc);
    }
    lg[lane] = acc + rb[lane];
    __syncthreads();
    if (lane == 0) {
        unsigned long long used = 0ull;
        int sel[K_]; float orig[K_];
        for (int k = 0; k < K_; ++k) {
            float best = -INFINITY; int bi = 0;
            for (int e = 0; e < E_; ++e) {
                if (used & (1ull << e)) continue;
                float v = lg[e] + bs[e];
                if (v > best) { best = v; bi = e; }   // strict > : lowest idx on tie
            }
            used |= (1ull << bi);
            sel[k] = bi; orig[k] = lg[bi];
        }
        float s[K_]; float sum = 0.f;
        for (int k = 0; k < K_; ++k) { s[k] = 1.f/(1.f + __expf(-orig[k])); sum += s[k]; }
        sum = fmaxf(sum, 1e-12f);
        for (int k = 0; k < K_; ++k) {
            idx_out[t*K_ + k] = sel[k];
            gate_out[t*K_ + k] = s[k] / sum;
        }
    }
}

// ---------------------------------------------------------------------------
// Build per-expert token lists + flattened row-block work list (single block).
// ---------------------------------------------------------------------------
__global__ __launch_bounds__(256) void moe_build(
    const int* __restrict__ idx, const float* __restrict__ gates,
    int* __restrict__ cnts, int* __restrict__ offs,
    int* __restrict__ entry_token, float* __restrict__ entry_gate,
    int* __restrict__ pair_pos,
    int* __restrict__ blk_e, int* __restrict__ blk_ro, int* __restrict__ nwork)
{
    __shared__ int c[E_];
    __shared__ int run[E_];
    const int tid = threadIdx.x;
    if (tid < E_) c[tid] = 0;
    __syncthreads();
    for (int p = tid; p < NPAIR; p += 256) atomicAdd(&c[idx[p]], 1);
    __syncthreads();
    if (tid == 0) {
        int o = 0;
        for (int e = 0; e < E_; ++e) { run[e] = o; offs[e] = o; cnts[e] = c[e]; o += c[e]; }
        offs[E_] = NPAIR;   // shared-expert entries
        cnts[E_] = T_;
        int nb = 0;
        for (int e = 0; e <= E_; ++e) {
            int n = (e < E_) ? c[e] : T_;
            for (int ro = 0; ro < n; ro += BM) { blk_e[nb] = e; blk_ro[nb] = ro; ++nb; }
        }
        nwork[0] = nb;
    }
    __syncthreads();
    for (int p = tid; p < NPAIR; p += 256) {
        int e = idx[p];
        int pos = atomicAdd(&run[e], 1);
        entry_token[pos] = p / K_;
        entry_gate[pos]  = gates[p];
        pair_pos[p]      = pos;
    }
    for (int t = tid; t < T_; t += 256) {
        entry_token[NPAIR + t] = t;
        entry_gate[NPAIR + t]  = 1.0f;
    }
}

// ---------------------------------------------------------------------------
// Stage 1: h1 = silu(X w1^T + b1) * (X w3^T + b3) -> bf16
// Minimal 2-phase: STAGE(t+1) issued BEFORE compute(t); one vmcnt(0)+barrier
// per K-step. Dbuf LDS 48 KB -> 3 blocks/CU. gload_lds staging, XOR swizzles
// (linear LDS dest + pre-swizzled global source + swizzled read).
// ---------------------------------------------------------------------------
__global__ __launch_bounds__(256, 3) void moe_stage1(
    const ushort* __restrict__ xbf,
    const float* __restrict__ w1, const float* __restrict__ b1,
    const float* __restrict__ w3, const float* __restrict__ b3,
    const float* __restrict__ sw1, const float* __restrict__ sb1,
    const float* __restrict__ sw3, const float* __restrict__ sb3,
    const int* __restrict__ cnts, const int* __restrict__ offs,
    const int* __restrict__ entry_token,
    const int* __restrict__ blk_e, const int* __restrict__ blk_ro,
    const int* __restrict__ nwork,
    ushort* __restrict__ h1buf)
{
    const int w = blockIdx.x;
    if (w >= nwork[0]) return;
    const int e  = blk_e[w];
    const int ro = blk_ro[w];
    const int itile = blockIdx.y;   // 0..I_/BN-1
    const int n = cnts[e];
    const int off = offs[e];
    const int rows = min(BM, n - ro);
    const float* W1 = (e < E_) ? (w1 + (size_t)e*I_*H_) : sw1;
    const float* W3 = (e < E_) ? (w3 + (size_t)e*I_*H_) : sw3;
    const float* B1 = (e < E_) ? (b1 + (size_t)e*I_) : sb1;
    const float* B3 = (e < E_) ? (b3 + (size_t)e*I_) : sb3;

    __shared__ __align__(16) ushort XL [2][BM*BKS];   // 2 x 8 KB
    __shared__ __align__(16) float  W1L[2][BN*BKS];   // 2 x 8 KB
    __shared__ __align__(16) float  W3L[2][BN*BKS];   // 2 x 8 KB -> 48 KB

    const int tid  = threadIdx.x;
    const int lane = tid & 63;
    const int wid  = tid >> 6;          // 0..3
    const int wm   = wid >> 1;          // 0..1 -> 64 rows
    const int wn   = wid & 1;           // 0..1 -> 32 cols
    const int l15  = lane & 15;
    const int lg   = lane >> 4;         // 0..3

    // --- staging sources (K-invariant, pre-swizzled) ---
    // X tile [128][32]bf16: 8 issues of 1KB (16 rows x 64B each).
    //   lane -> row j*16+(lane>>2), 16B chunk (lane&3); swz: ^((row>>1)&3).
    // W tiles [64][32]f32: 8 issues of 1KB (8 rows x 128B each).
    //   lane -> row j*8+(lane>>3), 16B chunk (lane&7); swz: ^(row&7).
    const ushort* xsrc[2];
    const float* w1src[2];
    const float* w3src[2];
    #pragma unroll
    for (int i = 0; i < 2; ++i) {
        const int j = wid*2 + i;
        const int rX = j*16 + (lane >> 2);
        const int cX = (lane & 3) ^ ((rX >> 1) & 3);
        xsrc[i] = xbf + (size_t)entry_token[off + ro + rX]*H_ + cX*8;
        const int rW = j*8 + (lane >> 3);
        const int cW = (lane & 7) ^ (rW & 7);
        w1src[i] = W1 + (size_t)(itile*BN + rW)*H_ + cW*4;
        w3src[i] = W3 + (size_t)(itile*BN + rW)*H_ + cW*4;
    }

    f32x4 acc1[4][2] = {};
    f32x4 acc3[4][2] = {};

    #define STAGE1(t, buf)                                                        \
        do {                                                                      \
            const int kc_ = (t) * BKS;                                            \
            _Pragma("unroll")                                                     \
            for (int i_ = 0; i_ < 2; ++i_) {                                      \
                gload16(xsrc[i_] + kc_,  (char*)&XL [buf][0] + (wid*2 + i_)*1024);\
                gload16(w1src[i_] + kc_, (char*)&W1L[buf][0] + (wid*2 + i_)*1024);\
                gload16(w3src[i_] + kc_, (char*)&W3L[buf][0] + (wid*2 + i_)*1024);\
            }                                                                     \
        } while (0)

    STAGE1(0, 0);
    STEP_SYNC();

    for (int t = 0; t < NT1; ++t) {
        const int cur = t & 1;
        if (t + 1 < NT1) STAGE1(t + 1, cur ^ 1);
        __builtin_amdgcn_sched_barrier(0);   // keep stage issues ahead of compute
        // ---- compute current tile (K=32) ----
        bf16x8 a[4];
        #pragma unroll
        for (int fm = 0; fm < 4; ++fm) {
            const int rr = wm*64 + fm*16 + l15;
            a[fm] = *reinterpret_cast<const bf16x8*>(
                (const char*)&XL[cur][0] + rr*64 + ((lg ^ ((rr >> 1) & 3)) << 4));
        }
        bf16x8 b1f[2], b3f[2];
        #pragma unroll
        for (int fn = 0; fn < 2; ++fn) {
            const int rw = wn*32 + fn*16 + l15;
            const int c0 = ((2*lg)     ^ (rw & 7)) << 4;
            const int c1 = ((2*lg + 1) ^ (rw & 7)) << 4;
            const char* p1 = (const char*)&W1L[cur][0] + rw*128;
            b1f[fn] = cvt8pk(*reinterpret_cast<const f32x4*>(p1 + c0),
                             *reinterpret_cast<const f32x4*>(p1 + c1));
            const char* p3 = (const char*)&W3L[cur][0] + rw*128;
            b3f[fn] = cvt8pk(*reinterpret_cast<const f32x4*>(p3 + c0),
                             *reinterpret_cast<const f32x4*>(p3 + c1));
        }
        #pragma unroll
        for (int fm = 0; fm < 4; ++fm) {
            #pragma unroll
            for (int fn = 0; fn < 2; ++fn) {
                acc1[fm][fn] = __builtin_amdgcn_mfma_f32_16x16x32_bf16(a[fm], b1f[fn], acc1[fm][fn], 0, 0, 0);
                acc3[fm][fn] = __builtin_amdgcn_mfma_f32_16x16x32_bf16(a[fm], b3f[fn], acc3[fm][fn], 0, 0, 0);
            }
        }
        if (t + 1 < NT1) STEP_SYNC();
    }
    #undef STAGE1

    // epilogue: silu(z1)*z3 -> bf16
    #pragma unroll
    for (int fm = 0; fm < 4; ++fm) {
        #pragma unroll
        for (int fn = 0; fn < 2; ++fn) {
            const int col = itile*BN + wn*32 + fn*16 + l15;
            const float bv1 = B1[col];
            const float bv3 = B3[col];
            #pragma unroll
            for (int j = 0; j < 4; ++j) {
                const int rl = wm*64 + fm*16 + lg*4 + j;   // C/D: row=(lane>>4)*4+reg, col=lane&15
                if (rl < rows) {
                    float z1 = acc1[fm][fn][j] + bv1;
                    float z3 = acc3[fm][fn][j] + bv3;
                    float h = z1 / (1.f + __expf(-z1)) * z3;
                    h1buf[(size_t)(off+ro+rl)*I_ + col] = f2bf(h);
                }
            }
        }
    }
}

// ---------------------------------------------------------------------------
// Stage 2: y = gate * (h1 @ w2^T + b2) -> fp32. Same 2-phase template.
// Dbuf LDS 32 KB -> 4 blocks/CU.
// ---------------------------------------------------------------------------
__global__ __launch_bounds__(256, 4) void moe_stage2(
    const ushort* __restrict__ h1buf,
    const float* __restrict__ w2, const float* __restrict__ b2,
    const float* __restrict__ sw2, const float* __restrict__ sb2,
    const int* __restrict__ cnts, const int* __restrict__ offs,
    const float* __restrict__ entry_gate,
    const int* __restrict__ blk_e, const int* __restrict__ blk_ro,
    const int* __restrict__ nwork,
    float* __restrict__ ybuf)
{
    const int w = blockIdx.x;
    if (w >= nwork[0]) return;
    const int e  = blk_e[w];
    const int ro = blk_ro[w];
    const int htile = blockIdx.y;   // 0..H_/BN-1
    const int n = cnts[e];
    const int off = offs[e];
    const int rows = min(BM, n - ro);
    const float* W2 = (e < E_) ? (w2 + (size_t)e*H_*I_) : sw2;
    const float* B2 = (e < E_) ? (b2 + (size_t)e*H_) : sb2;

    __shared__ __align__(16) ushort HL [2][BM*BKS];   // 2 x 8 KB
    __shared__ __align__(16) float  W2L[2][BN*BKS];   // 2 x 8 KB -> 32 KB

    const int tid  = threadIdx.x;
    const int lane = tid & 63;
    const int wid  = tid >> 6;          // 0..3
    const int wm   = wid >> 1;
    const int wn   = wid & 1;
    const int l15  = lane & 15;
    const int lg   = lane >> 4;

    const ushort* hsrc[2];
    const float*  wsrc[2];
    #pragma unroll
    for (int i = 0; i < 2; ++i) {
        const int j = wid*2 + i;
        const int rH = j*16 + (lane >> 2);
        const int cH = (lane & 3) ^ ((rH >> 1) & 3);
        hsrc[i] = h1buf + (size_t)(off + ro + rH)*I_ + cH*8;
        const int rW = j*8 + (lane >> 3);
        const int cW = (lane & 7) ^ (rW & 7);
        wsrc[i] = W2 + (size_t)(htile*BN + rW)*I_ + cW*4;
    }

    f32x4 acc[4][2] = {};

    #define STAGE2(t, buf)                                                        \
        do {                                                                      \
            const int kc_ = (t) * BKS;                                            \
            _Pragma("unroll")                                                     \
            for (int i_ = 0; i_ < 2; ++i_) {                                      \
                gload16(hsrc[i_] + kc_, (char*)&HL [buf][0] + (wid*2 + i_)*1024); \
                gload16(wsrc[i_] + kc_, (char*)&W2L[buf][0] + (wid*2 + i_)*1024); \
            }                                                                     \
        } while (0)

    STAGE2(0, 0);
    STEP_SYNC();

    for (int t = 0; t < NT2; ++t) {
        const int cur = t & 1;
        if (t + 1 < NT2) STAGE2(t + 1, cur ^ 1);
        __builtin_amdgcn_sched_barrier(0);
        bf16x8 a[4];
        #pragma unroll
        for (int fm = 0; fm < 4; ++fm) {
            const int rr = wm*64 + fm*16 + l15;
            a[fm] = *reinterpret_cast<const bf16x8*>(
                (const char*)&HL[cur][0] + rr*64 + ((lg ^ ((rr >> 1) & 3)) << 4));
        }
        bf16x8 bf[2];
        #pragma unroll
        for (int fn = 0; fn < 2; ++fn) {
            const int rw = wn*32 + fn*16 + l15;
            const int c0 = ((2*lg)     ^ (rw & 7)) << 4;
            const int c1 = ((2*lg + 1) ^ (rw & 7)) << 4;
            const char* p = (const char*)&W2L[cur][0] + rw*128;
            bf[fn] = cvt8pk(*reinterpret_cast<const f32x4*>(p + c0),
                            *reinterpret_cast<const f32x4*>(p + c1));
        }
        #pragma unroll
        for (int fm = 0; fm < 4; ++fm) {
            #pragma unroll
            for (int fn = 0; fn < 2; ++fn) {
                acc[fm][fn] = __builtin_amdgcn_mfma_f32_16x16x32_bf16(a[fm], bf[fn], acc[fm][fn], 0, 0, 0);
            }
        }
        if (t + 1 < NT2) STEP_SYNC();
    }
    #undef STAGE2

    #pragma unroll
    for (int fm = 0; fm < 4; ++fm) {
        #pragma unroll
        for (int fn = 0; fn < 2; ++fn) {
            const int col = htile*BN + wn*32 + fn*16 + l15;
            const float bv = B2[col];
            #pragma unroll
            for (int j = 0; j < 4; ++j) {
                const int rl = wm*64 + fm*16 + lg*4 + j;
                if (rl < rows) {
                    const float g = entry_gate[off + ro + rl];
                    ybuf[(size_t)(off+ro+rl)*H_ + col] = (acc[fm][fn][j] + bv) * g;
                }
            }
        }
    }
}

// ---------------------------------------------------------------------------
// Combine: out[t] = y_shared[t] + sum_k y_routed[pair_pos[t,k]]
// ---------------------------------------------------------------------------
__global__ __launch_bounds__(128) void moe_combine(
    const float* __restrict__ ybuf, const int* __restrict__ pair_pos,
    float* __restrict__ out)
{
    const int t = blockIdx.x;
    const int lane = threadIdx.x;     // 128 threads * 4 floats = 512
    const int h = lane * 4;
    const int p0 = pair_pos[t*K_+0], p1 = pair_pos[t*K_+1];
    const int p2 = pair_pos[t*K_+2], p3 = pair_pos[t*K_+3];
    float4 a  = *reinterpret_cast<const float4*>(ybuf + (size_t)(NPAIR+t)*H_ + h);
    float4 v0 = *reinterpret_cast<const float4*>(ybuf + (size_t)p0*H_ + h);
    float4 v1 = *reinterpret_cast<const float4*>(ybuf + (size_t)p1*H_ + h);
    float4 v2 = *reinterpret_cast<const float4*>(ybuf + (size_t)p2*H_ + h);
    float4 v3 = *reinterpret_cast<const float4*>(ybuf + (size_t)p3*H_ + h);
    float4 r;
    r.x = a.x + v0.x + v1.x + v2.x + v3.x;
    r.y = a.y + v0.y + v1.y + v2.y + v3.y;
    r.z = a.z + v0.z + v1.z + v2.z + v3.z;
    r.w = a.w + v0.w + v1.w + v2.w + v3.w;
    *reinterpret_cast<float4*>(out + (size_t)t*H_ + h) = r;
}

extern "C" void kernel_launch(void* const* d_in, const int* in_sizes, int n_in,
                              void* d_out, int out_size, void* d_ws, size_t ws_size,
                              hipStream_t stream)
{
    const float* x   = (const float*)d_in[0];
    const float* rw  = (const float*)d_in[1];
    const float* rb  = (const float*)d_in[2];
    const float* eb  = (const float*)d_in[3];
    const float* sw1 = (const float*)d_in[4];
    const float* sb1 = (const float*)d_in[5];
    const float* sw2 = (const float*)d_in[6];
    const float* sb2 = (const float*)d_in[7];
    const float* sw3 = (const float*)d_in[8];
    const float* sb3 = (const float*)d_in[9];
    const float* w1  = (const float*)d_in[10];
    const float* b1  = (const float*)d_in[11];
    const float* w2  = (const float*)d_in[12];
    const float* b2  = (const float*)d_in[13];
    const float* w3  = (const float*)d_in[14];
    const float* b3  = (const float*)d_in[15];
    float* out = (float*)d_out;

    char* p = (char*)d_ws;
    auto take = [&](size_t bytes) { char* q = p; p += (bytes + 255) & ~(size_t)255; return q; };
    int*    idxb  = (int*)   take((size_t)NPAIR*4);
    float*  gateb = (float*) take((size_t)NPAIR*4);
    int*    cnts  = (int*)   take((E_+1)*4);
    int*    offs  = (int*)   take((E_+1)*4);
    int*    etok  = (int*)   take((size_t)NENT*4);
    float*  egate = (float*) take((size_t)NENT*4);
    int*    ppos  = (int*)   take((size_t)NPAIR*4);
    int*    blk_e = (int*)   take((size_t)MAXWORK*4);
    int*    blk_ro= (int*)   take((size_t)MAXWORK*4);
    int*    nwork = (int*)   take(4);
    ushort* xbf   = (ushort*)take((size_t)T_*H_*2);
    ushort* h1buf = (ushort*)take((size_t)NENT*I_*2);
    float*  ybuf  = (float*) take((size_t)NENT*H_*4);

    x_cvt      <<<(T_*H_)/(256*4), 256, 0, stream>>>(x, xbf);
    moe_router <<<T_, 64, 0, stream>>>(x, rw, rb, eb, idxb, gateb);
    moe_build  <<<1, 256, 0, stream>>>(idxb, gateb, cnts, offs, etok, egate, ppos,
                                       blk_e, blk_ro, nwork);
    moe_stage1 <<<dim3(MAXWORK, I_/BN), 256, 0, stream>>>(xbf, w1, b1, w3, b3,
                                                          sw1, sb1, sw3, sb3,
                                                          cnts, offs, etok,
                                                          blk_e, blk_ro, nwork, h1buf);
    moe_stage2 <<<dim3(MAXWORK, H_/BN), 256, 0, stream>>>(h1buf, w2, b2, sw2, sb2,
                                                          cnts, offs, egate,
                                                          blk_e, blk_ro, nwork, ybuf);
    moe_combine<<<T_, 128, 0, stream>>>(ybuf, ppos, out);
}

// Round 8
// 212.384 us; speedup vs baseline: 1.0201x; 1.0201x over previous
//
#include <hip/hip_runtime.h>
#include <math.h>

// Problem constants (fixed by the reference)
#define T_    1024      // B*S tokens
#define H_    512       // hidden
#define I_    1024      // intermediate
#define E_    64        // routed experts
#define K_    4         // top-k
#define NPAIR (T_*K_)   // 4096 routed (token,slot) pairs
#define NENT  (NPAIR + T_)  // + shared-expert entries at [NPAIR + t]

#define BM 128          // rows per work block
#define BN 64           // output cols per block
#define BKS 32          // k-step (elements)
#define MAXWORK 160
#define NT1 (H_/BKS)    // 16
#define NT2 (I_/BKS)    // 32

typedef float  f32x4  __attribute__((ext_vector_type(4)));
typedef short  bf16x8 __attribute__((ext_vector_type(8)));

// Counted-wait barrier: keep N oldest-pending global loads IN FLIGHT across
// the barrier (T4). lgkmcnt(0) retires this wave's ds_reads so the buffer
// being re-staged after the barrier is safe to overwrite.
#define WAIT_BAR(N) asm volatile("s_waitcnt vmcnt(" #N ") lgkmcnt(0)\n\ts_barrier" ::: "memory")

__device__ __forceinline__ ushort f2bf(float f) {
    uint u = __float_as_uint(f);
    u += 0x7fffu + ((u >> 16) & 1u);   // round-to-nearest-even
    return (ushort)(u >> 16);
}
// packed f32->bf16 (RNE, same result as f2bf) - 1 VALU op per 2 elements
__device__ __forceinline__ bf16x8 cvt8pk(f32x4 a, f32x4 b) {
    union { uint u[4]; bf16x8 v; } r;
    asm("v_cvt_pk_bf16_f32 %0, %1, %2" : "=v"(r.u[0]) : "v"(a[0]), "v"(a[1]));
    asm("v_cvt_pk_bf16_f32 %0, %1, %2" : "=v"(r.u[1]) : "v"(a[2]), "v"(a[3]));
    asm("v_cvt_pk_bf16_f32 %0, %1, %2" : "=v"(r.u[2]) : "v"(b[0]), "v"(b[1]));
    asm("v_cvt_pk_bf16_f32 %0, %1, %2" : "=v"(r.u[3]) : "v"(b[2]), "v"(b[3]));
    return r.v;
}

// async global->LDS, 16B per lane; LDS dest = wave-uniform base + lane*16
__device__ __forceinline__ void gload16(const void* g, void* lds) {
    __builtin_amdgcn_global_load_lds(
        (const __attribute__((address_space(1))) unsigned int*)g,
        (__attribute__((address_space(3))) unsigned int*)lds, 16, 0, 0);
}

// ---------------------------------------------------------------------------
// x -> bf16 pre-pass (2 MB, ~2 us)
// ---------------------------------------------------------------------------
__global__ __launch_bounds__(256) void x_cvt(const float* __restrict__ x,
                                             ushort* __restrict__ xb)
{
    const int i = blockIdx.x*256 + threadIdx.x;     // T_*H_/4 float4s
    float4 v = reinterpret_cast<const float4*>(x)[i];
    reinterpret_cast<ushort4*>(xb)[i] =
        make_ushort4(f2bf(v.x), f2bf(v.y), f2bf(v.z), f2bf(v.w));
}

// ---------------------------------------------------------------------------
// Router: one 64-thread block per token.
// ---------------------------------------------------------------------------
__global__ __launch_bounds__(64) void moe_router(
    const float* __restrict__ x, const float* __restrict__ rw,
    const float* __restrict__ rb, const float* __restrict__ eb,
    int* __restrict__ idx_out, float* __restrict__ gate_out)
{
    const int t = blockIdx.x;
    const int lane = threadIdx.x;  // 0..63
    __shared__ float xs[H_];
    __shared__ float lg[E_];
    __shared__ float bs[E_];
    for (int i = lane; i < H_; i += 64) xs[i] = x[(size_t)t*H_ + i];
    bs[lane] = eb[lane];
    __syncthreads();
    float acc = 0.f;
    const float* wrow = rw + (size_t)lane*H_;
    for (int k = 0; k < H_; k += 4) {
        float4 w4 = *reinterpret_cast<const float4*>(wrow + k);
        acc = fmaf(xs[k+0], w4.x, acc);
        acc = fmaf(xs[k+1], w4.y, acc);
        acc = fmaf(xs[k+2], w4.z, acc);
        acc = fmaf(xs[k+3], w4.w, acc);
    }
    lg[lane] = acc + rb[lane];
    __syncthreads();
    if (lane == 0) {
        unsigned long long used = 0ull;
        int sel[K_]; float orig[K_];
        for (int k = 0; k < K_; ++k) {
            float best = -INFINITY; int bi = 0;
            for (int e = 0; e < E_; ++e) {
                if (used & (1ull << e)) continue;
                float v = lg[e] + bs[e];
                if (v > best) { best = v; bi = e; }   // strict > : lowest idx on tie
            }
            used |= (1ull << bi);
            sel[k] = bi; orig[k] = lg[bi];
        }
        float s[K_]; float sum = 0.f;
        for (int k = 0; k < K_; ++k) { s[k] = 1.f/(1.f + __expf(-orig[k])); sum += s[k]; }
        sum = fmaxf(sum, 1e-12f);
        for (int k = 0; k < K_; ++k) {
            idx_out[t*K_ + k] = sel[k];
            gate_out[t*K_ + k] = s[k] / sum;
        }
    }
}

// ---------------------------------------------------------------------------
// Build per-expert token lists + flattened row-block work list (single block).
// ---------------------------------------------------------------------------
__global__ __launch_bounds__(256) void moe_build(
    const int* __restrict__ idx, const float* __restrict__ gates,
    int* __restrict__ cnts, int* __restrict__ offs,
    int* __restrict__ entry_token, float* __restrict__ entry_gate,
    int* __restrict__ pair_pos,
    int* __restrict__ blk_e, int* __restrict__ blk_ro, int* __restrict__ nwork)
{
    __shared__ int c[E_];
    __shared__ int run[E_];
    const int tid = threadIdx.x;
    if (tid < E_) c[tid] = 0;
    __syncthreads();
    for (int p = tid; p < NPAIR; p += 256) atomicAdd(&c[idx[p]], 1);
    __syncthreads();
    if (tid == 0) {
        int o = 0;
        for (int e = 0; e < E_; ++e) { run[e] = o; offs[e] = o; cnts[e] = c[e]; o += c[e]; }
        offs[E_] = NPAIR;   // shared-expert entries
        cnts[E_] = T_;
        int nb = 0;
        for (int e = 0; e <= E_; ++e) {
            int n = (e < E_) ? c[e] : T_;
            for (int ro = 0; ro < n; ro += BM) { blk_e[nb] = e; blk_ro[nb] = ro; ++nb; }
        }
        nwork[0] = nb;
    }
    __syncthreads();
    for (int p = tid; p < NPAIR; p += 256) {
        int e = idx[p];
        int pos = atomicAdd(&run[e], 1);
        entry_token[pos] = p / K_;
        entry_gate[pos]  = gates[p];
        pair_pos[p]      = pos;
    }
    for (int t = tid; t < T_; t += 256) {
        entry_token[NPAIR + t] = t;
        entry_gate[NPAIR + t]  = 1.0f;
    }
}

// ---------------------------------------------------------------------------
// Stage 1: h1 = silu(X w1^T + b1) * (X w3^T + b3) -> bf16
// T4 counted-vmcnt 3-buffer pipeline: tile t+2 staged at step t; per-step
// wait vmcnt(6) keeps tile t+1's 6 loads/wave in flight across the barrier.
// LDS 72 KB -> 2 blocks/CU.
// ---------------------------------------------------------------------------
__global__ __launch_bounds__(256, 2) void moe_stage1(
    const ushort* __restrict__ xbf,
    const float* __restrict__ w1, const float* __restrict__ b1,
    const float* __restrict__ w3, const float* __restrict__ b3,
    const float* __restrict__ sw1, const float* __restrict__ sb1,
    const float* __restrict__ sw3, const float* __restrict__ sb3,
    const int* __restrict__ cnts, const int* __restrict__ offs,
    const int* __restrict__ entry_token,
    const int* __restrict__ blk_e, const int* __restrict__ blk_ro,
    const int* __restrict__ nwork,
    ushort* __restrict__ h1buf)
{
    const int w = blockIdx.x;
    if (w >= nwork[0]) return;
    const int e  = blk_e[w];
    const int ro = blk_ro[w];
    const int itile = blockIdx.y;   // 0..I_/BN-1
    const int n = cnts[e];
    const int off = offs[e];
    const int rows = min(BM, n - ro);
    const float* W1 = (e < E_) ? (w1 + (size_t)e*I_*H_) : sw1;
    const float* W3 = (e < E_) ? (w3 + (size_t)e*I_*H_) : sw3;
    const float* B1 = (e < E_) ? (b1 + (size_t)e*I_) : sb1;
    const float* B3 = (e < E_) ? (b3 + (size_t)e*I_) : sb3;

    __shared__ __align__(16) ushort XL [3][BM*BKS];   // 3 x 8 KB
    __shared__ __align__(16) float  W1L[3][BN*BKS];   // 3 x 8 KB
    __shared__ __align__(16) float  W3L[3][BN*BKS];   // 3 x 8 KB -> 72 KB

    const int tid  = threadIdx.x;
    const int lane = tid & 63;
    const int wid  = tid >> 6;          // 0..3
    const int wm   = wid >> 1;          // 0..1 -> 64 rows
    const int wn   = wid & 1;           // 0..1 -> 32 cols
    const int l15  = lane & 15;
    const int lg   = lane >> 4;         // 0..3

    // --- staging sources (K-invariant, pre-swizzled; same as verified R7) ---
    const ushort* xsrc[2];
    const float* w1src[2];
    const float* w3src[2];
    #pragma unroll
    for (int i = 0; i < 2; ++i) {
        const int j = wid*2 + i;
        const int rX = j*16 + (lane >> 2);
        const int cX = (lane & 3) ^ ((rX >> 1) & 3);
        xsrc[i] = xbf + (size_t)entry_token[off + ro + rX]*H_ + cX*8;
        const int rW = j*8 + (lane >> 3);
        const int cW = (lane & 7) ^ (rW & 7);
        w1src[i] = W1 + (size_t)(itile*BN + rW)*H_ + cW*4;
        w3src[i] = W3 + (size_t)(itile*BN + rW)*H_ + cW*4;
    }

    f32x4 acc1[4][2] = {};
    f32x4 acc3[4][2] = {};

    #define STAGE1(t, buf)                                                        \
        do {                                                                      \
            const int kc_ = (t) * BKS;                                            \
            _Pragma("unroll")                                                     \
            for (int i_ = 0; i_ < 2; ++i_) {                                      \
                gload16(xsrc[i_] + kc_,  (char*)&XL [buf][0] + (wid*2 + i_)*1024);\
                gload16(w1src[i_] + kc_, (char*)&W1L[buf][0] + (wid*2 + i_)*1024);\
                gload16(w3src[i_] + kc_, (char*)&W3L[buf][0] + (wid*2 + i_)*1024);\
            }                                                                     \
        } while (0)

    // prologue: two tiles in flight (12 loads/wave)
    STAGE1(0, 0);
    STAGE1(1, 1);

    #pragma unroll
    for (int t = 0; t < NT1; ++t) {
        // retire tile t's 6 loads; keep tile t+1's 6 in flight (except tail)
        if (t < NT1 - 1) WAIT_BAR(6); else WAIT_BAR(0);
        if (t + 2 < NT1) STAGE1(t + 2, (t + 2) % 3);
        __builtin_amdgcn_sched_barrier(0);   // stage issues stay ahead of compute
        const int cur = t % 3;
        // ---- compute tile t (K=32) ----
        bf16x8 a[4];
        #pragma unroll
        for (int fm = 0; fm < 4; ++fm) {
            const int rr = wm*64 + fm*16 + l15;
            a[fm] = *reinterpret_cast<const bf16x8*>(
                (const char*)&XL[cur][0] + rr*64 + ((lg ^ ((rr >> 1) & 3)) << 4));
        }
        bf16x8 b1f[2], b3f[2];
        #pragma unroll
        for (int fn = 0; fn < 2; ++fn) {
            const int rw = wn*32 + fn*16 + l15;
            const int c0 = ((2*lg)     ^ (rw & 7)) << 4;
            const int c1 = ((2*lg + 1) ^ (rw & 7)) << 4;
            const char* p1 = (const char*)&W1L[cur][0] + rw*128;
            b1f[fn] = cvt8pk(*reinterpret_cast<const f32x4*>(p1 + c0),
                             *reinterpret_cast<const f32x4*>(p1 + c1));
            const char* p3 = (const char*)&W3L[cur][0] + rw*128;
            b3f[fn] = cvt8pk(*reinterpret_cast<const f32x4*>(p3 + c0),
                             *reinterpret_cast<const f32x4*>(p3 + c1));
        }
        __builtin_amdgcn_s_setprio(1);
        #pragma unroll
        for (int fm = 0; fm < 4; ++fm) {
            #pragma unroll
            for (int fn = 0; fn < 2; ++fn) {
                acc1[fm][fn] = __builtin_amdgcn_mfma_f32_16x16x32_bf16(a[fm], b1f[fn], acc1[fm][fn], 0, 0, 0);
                acc3[fm][fn] = __builtin_amdgcn_mfma_f32_16x16x32_bf16(a[fm], b3f[fn], acc3[fm][fn], 0, 0, 0);
            }
        }
        __builtin_amdgcn_s_setprio(0);
    }
    #undef STAGE1

    // epilogue: silu(z1)*z3 -> bf16
    #pragma unroll
    for (int fm = 0; fm < 4; ++fm) {
        #pragma unroll
        for (int fn = 0; fn < 2; ++fn) {
            const int col = itile*BN + wn*32 + fn*16 + l15;
            const float bv1 = B1[col];
            const float bv3 = B3[col];
            #pragma unroll
            for (int j = 0; j < 4; ++j) {
                const int rl = wm*64 + fm*16 + lg*4 + j;   // C/D: row=(lane>>4)*4+reg, col=lane&15
                if (rl < rows) {
                    float z1 = acc1[fm][fn][j] + bv1;
                    float z3 = acc3[fm][fn][j] + bv3;
                    float h = z1 / (1.f + __expf(-z1)) * z3;
                    h1buf[(size_t)(off+ro+rl)*I_ + col] = f2bf(h);
                }
            }
        }
    }
}

// ---------------------------------------------------------------------------
// Stage 2: y = gate * (h1 @ w2^T + b2) -> fp32. Same T4 template.
// LDS 48 KB -> 3 blocks/CU. 4 loads/wave/tile -> steady wait vmcnt(4).
// ---------------------------------------------------------------------------
__global__ __launch_bounds__(256, 3) void moe_stage2(
    const ushort* __restrict__ h1buf,
    const float* __restrict__ w2, const float* __restrict__ b2,
    const float* __restrict__ sw2, const float* __restrict__ sb2,
    const int* __restrict__ cnts, const int* __restrict__ offs,
    const float* __restrict__ entry_gate,
    const int* __restrict__ blk_e, const int* __restrict__ blk_ro,
    const int* __restrict__ nwork,
    float* __restrict__ ybuf)
{
    const int w = blockIdx.x;
    if (w >= nwork[0]) return;
    const int e  = blk_e[w];
    const int ro = blk_ro[w];
    const int htile = blockIdx.y;   // 0..H_/BN-1
    const int n = cnts[e];
    const int off = offs[e];
    const int rows = min(BM, n - ro);
    const float* W2 = (e < E_) ? (w2 + (size_t)e*H_*I_) : sw2;
    const float* B2 = (e < E_) ? (b2 + (size_t)e*H_) : sb2;

    __shared__ __align__(16) ushort HL [3][BM*BKS];   // 3 x 8 KB
    __shared__ __align__(16) float  W2L[3][BN*BKS];   // 3 x 8 KB -> 48 KB

    const int tid  = threadIdx.x;
    const int lane = tid & 63;
    const int wid  = tid >> 6;          // 0..3
    const int wm   = wid >> 1;
    const int wn   = wid & 1;
    const int l15  = lane & 15;
    const int lg   = lane >> 4;

    const ushort* hsrc[2];
    const float*  wsrc[2];
    #pragma unroll
    for (int i = 0; i < 2; ++i) {
        const int j = wid*2 + i;
        const int rH = j*16 + (lane >> 2);
        const int cH = (lane & 3) ^ ((rH >> 1) & 3);
        hsrc[i] = h1buf + (size_t)(off + ro + rH)*I_ + cH*8;
        const int rW = j*8 + (lane >> 3);
        const int cW = (lane & 7) ^ (rW & 7);
        wsrc[i] = W2 + (size_t)(htile*BN + rW)*I_ + cW*4;
    }

    f32x4 acc[4][2] = {};

    #define STAGE2(t, buf)                                                        \
        do {                                                                      \
            const int kc_ = (t) * BKS;                                            \
            _Pragma("unroll")                                                     \
            for (int i_ = 0; i_ < 2; ++i_) {                                      \
                gload16(hsrc[i_] + kc_, (char*)&HL [buf][0] + (wid*2 + i_)*1024); \
                gload16(wsrc[i_] + kc_, (char*)&W2L[buf][0] + (wid*2 + i_)*1024); \
            }                                                                     \
        } while (0)

    STAGE2(0, 0);
    STAGE2(1, 1);

    #pragma unroll
    for (int t = 0; t < NT2; ++t) {
        if (t < NT2 - 1) WAIT_BAR(4); else WAIT_BAR(0);
        if (t + 2 < NT2) STAGE2(t + 2, (t + 2) % 3);
        __builtin_amdgcn_sched_barrier(0);
        const int cur = t % 3;
        bf16x8 a[4];
        #pragma unroll
        for (int fm = 0; fm < 4; ++fm) {
            const int rr = wm*64 + fm*16 + l15;
            a[fm] = *reinterpret_cast<const bf16x8*>(
                (const char*)&HL[cur][0] + rr*64 + ((lg ^ ((rr >> 1) & 3)) << 4));
        }
        bf16x8 bf[2];
        #pragma unroll
        for (int fn = 0; fn < 2; ++fn) {
            const int rw = wn*32 + fn*16 + l15;
            const int c0 = ((2*lg)     ^ (rw & 7)) << 4;
            const int c1 = ((2*lg + 1) ^ (rw & 7)) << 4;
            const char* p = (const char*)&W2L[cur][0] + rw*128;
            bf[fn] = cvt8pk(*reinterpret_cast<const f32x4*>(p + c0),
                            *reinterpret_cast<const f32x4*>(p + c1));
        }
        __builtin_amdgcn_s_setprio(1);
        #pragma unroll
        for (int fm = 0; fm < 4; ++fm) {
            #pragma unroll
            for (int fn = 0; fn < 2; ++fn) {
                acc[fm][fn] = __builtin_amdgcn_mfma_f32_16x16x32_bf16(a[fm], bf[fn], acc[fm][fn], 0, 0, 0);
            }
        }
        __builtin_amdgcn_s_setprio(0);
    }
    #undef STAGE2

    #pragma unroll
    for (int fm = 0; fm < 4; ++fm) {
        #pragma unroll
        for (int fn = 0; fn < 2; ++fn) {
            const int col = htile*BN + wn*32 + fn*16 + l15;
            const float bv = B2[col];
            #pragma unroll
            for (int j = 0; j < 4; ++j) {
                const int rl = wm*64 + fm*16 + lg*4 + j;
                if (rl < rows) {
                    const float g = entry_gate[off + ro + rl];
                    ybuf[(size_t)(off+ro+rl)*H_ + col] = (acc[fm][fn][j] + bv) * g;
                }
            }
        }
    }
}

// ---------------------------------------------------------------------------
// Combine: out[t] = y_shared[t] + sum_k y_routed[pair_pos[t,k]]
// ---------------------------------------------------------------------------
__global__ __launch_bounds__(128) void moe_combine(
    const float* __restrict__ ybuf, const int* __restrict__ pair_pos,
    float* __restrict__ out)
{
    const int t = blockIdx.x;
    const int lane = threadIdx.x;     // 128 threads * 4 floats = 512
    const int h = lane * 4;
    const int p0 = pair_pos[t*K_+0], p1 = pair_pos[t*K_+1];
    const int p2 = pair_pos[t*K_+2], p3 = pair_pos[t*K_+3];
    float4 a  = *reinterpret_cast<const float4*>(ybuf + (size_t)(NPAIR+t)*H_ + h);
    float4 v0 = *reinterpret_cast<const float4*>(ybuf + (size_t)p0*H_ + h);
    float4 v1 = *reinterpret_cast<const float4*>(ybuf + (size_t)p1*H_ + h);
    float4 v2 = *reinterpret_cast<const float4*>(ybuf + (size_t)p2*H_ + h);
    float4 v3 = *reinterpret_cast<const float4*>(ybuf + (size_t)p3*H_ + h);
    float4 r;
    r.x = a.x + v0.x + v1.x + v2.x + v3.x;
    r.y = a.y + v0.y + v1.y + v2.y + v3.y;
    r.z = a.z + v0.z + v1.z + v2.z + v3.z;
    r.w = a.w + v0.w + v1.w + v2.w + v3.w;
    *reinterpret_cast<float4*>(out + (size_t)t*H_ + h) = r;
}

extern "C" void kernel_launch(void* const* d_in, const int* in_sizes, int n_in,
                              void* d_out, int out_size, void* d_ws, size_t ws_size,
                              hipStream_t stream)
{
    const float* x   = (const float*)d_in[0];
    const float* rw  = (const float*)d_in[1];
    const float* rb  = (const float*)d_in[2];
    const float* eb  = (const float*)d_in[3];
    const float* sw1 = (const float*)d_in[4];
    const float* sb1 = (const float*)d_in[5];
    const float* sw2 = (const float*)d_in[6];
    const float* sb2 = (const float*)d_in[7];
    const float* sw3 = (const float*)d_in[8];
    const float* sb3 = (const float*)d_in[9];
    const float* w1  = (const float*)d_in[10];
    const float* b1  = (const float*)d_in[11];
    const float* w2  = (const float*)d_in[12];
    const float* b2  = (const float*)d_in[13];
    const float* w3  = (const float*)d_in[14];
    const float* b3  = (const float*)d_in[15];
    float* out = (float*)d_out;

    char* p = (char*)d_ws;
    auto take = [&](size_t bytes) { char* q = p; p += (bytes + 255) & ~(size_t)255; return q; };
    int*    idxb  = (int*)   take((size_t)NPAIR*4);
    float*  gateb = (float*) take((size_t)NPAIR*4);
    int*    cnts  = (int*)   take((E_+1)*4);
    int*    offs  = (int*)   take((E_+1)*4);
    int*    etok  = (int*)   take((size_t)NENT*4);
    float*  egate = (float*) take((size_t)NENT*4);
    int*    ppos  = (int*)   take((size_t)NPAIR*4);
    int*    blk_e = (int*)   take((size_t)MAXWORK*4);
    int*    blk_ro= (int*)   take((size_t)MAXWORK*4);
    int*    nwork = (int*)   take(4);
    ushort* xbf   = (ushort*)take((size_t)T_*H_*2);
    ushort* h1buf = (ushort*)take((size_t)NENT*I_*2);
    float*  ybuf  = (float*) take((size_t)NENT*H_*4);

    x_cvt      <<<(T_*H_)/(256*4), 256, 0, stream>>>(x, xbf);
    moe_router <<<T_, 64, 0, stream>>>(x, rw, rb, eb, idxb, gateb);
    moe_build  <<<1, 256, 0, stream>>>(idxb, gateb, cnts, offs, etok, egate, ppos,
                                       blk_e, blk_ro, nwork);
    moe_stage1 <<<dim3(MAXWORK, I_/BN), 256, 0, stream>>>(xbf, w1, b1, w3, b3,
                                                          sw1, sb1, sw3, sb3,
                                                          cnts, offs, etok,
                                                          blk_e, blk_ro, nwork, h1buf);
    moe_stage2 <<<dim3(MAXWORK, H_/BN), 256, 0, stream>>>(h1buf, w2, b2, sw2, sb2,
                                                          cnts, offs, egate,
                                                          blk_e, blk_ro, nwork, ybuf);
    moe_combine<<<T_, 128, 0, stream>>>(ybuf, ppos, out);
}